// Round 6
// baseline (850.791 us; speedup 1.0000x reference)
//
#include <hip/hip_runtime.h>
#include <stdint.h>

// Problem: out[t,b,c,h,w] = (t - 64*x >= 0) * (uniform(fold_in(key(0),1)) <= 0.75)
// out shape (64,16,3,224,224) fp32; N = 154,140,672 < 2^32.
//
// Evidence so far: VALU-issue-bound on the 20-round threefry (irreducible,
// bit-exact, absmax=0 across R0/R3/R4/R5). R5's forced v_alignbit_b32 won
// -46.5 us => instruction count is the lever. R6 tests the last structural
// suspect for the remaining gap vs the ~65% sustained-issue ceiling:
// instruction footprint. R4/R5's fully-unrolled body was ~2400 instrs
// (~20 KB); this version rolls the t-loop (body ~600 instrs ~5 KB) and
// raises TBATCH to 16 to amortize x-loads/setup further.
static constexpr uint32_t T = 64;
static constexpr uint32_t M = 16u * 3u * 224u * 224u;  // 2,408,448 per timestep
static constexpr uint32_t TBATCH = 16;

// uniform = bitcast((bits>>9)|0x3F800000)-1 <= 0.75  <=>  bits <= 0xC00001FF
static constexpr uint32_t BITS_LE = 0xC00001FFu;

// One threefry round: x0 += x1; x1 = rotl(x1, 32-COMPL); x1 ^= x0.
// COMPL = complement shift, inline constant (free in src2).
#define TF_RND(COMPL)                                                   \
  x0 += x1;                                                             \
  asm("v_alignbit_b32 %0, %1, %1, " #COMPL : "=v"(x1) : "v"(x1));       \
  x1 ^= x0;

// Threefry-2x32, 20 rounds, counts=(0,j). JAX partitionable random_bits
// returns x0^x1. x0 starts at 0 so the key-inject is x0=k0; x1 arrives
// pre-injected (= j + k1). Rotations 13,15,26,6 / 17,29,16,24 ->
// complements 19,17,6,26 / 15,3,16,8. Bit-exact on HW (R0/R3/R4/R5).
__device__ __forceinline__ uint32_t tf2x32_xor(uint32_t k0, uint32_t k1,
                                               uint32_t ks2, uint32_t x1) {
  uint32_t x0 = k0;
  TF_RND(19) TF_RND(17) TF_RND(6)  TF_RND(26)
  x0 += k1;  x1 += ks2 + 1u;
  TF_RND(15) TF_RND(3)  TF_RND(16) TF_RND(8)
  x0 += ks2; x1 += k0 + 2u;
  TF_RND(19) TF_RND(17) TF_RND(6)  TF_RND(26)
  x0 += k0;  x1 += k1 + 3u;
  TF_RND(15) TF_RND(3)  TF_RND(16) TF_RND(8)
  x0 += k1;  x1 += ks2 + 4u;
  TF_RND(19) TF_RND(17) TF_RND(6)  TF_RND(26)
  x0 += ks2; x1 += k0 + 5u;
  return x0 ^ x1;
}

// grid = (M/8/256, T/TBATCH) = (1176, 4); blockIdx.y selects 16 consecutive
// t. Each thread: 8 consecutive spatial elements x 16 timesteps, t-loop
// rolled to keep the instruction footprint small (~5 KB).
__global__ __launch_bounds__(256) void spike_encode(
    const float* __restrict__ x, float* __restrict__ out,
    uint32_t rk0, uint32_t rk1) {
  const uint32_t m8 = (blockIdx.x * 256u + threadIdx.x) * 8u;
  const uint32_t t0 = blockIdx.y * TBATCH;

  const float4 xa = *reinterpret_cast<const float4*>(x + m8);
  const float4 xb = *reinterpret_cast<const float4*>(x + m8 + 4);

  const uint32_t ks2 = rk0 ^ rk1 ^ 0x1BD11BDAu;
  // Pre-injected count base for (t0, m8); advances by M per timestep.
  uint32_t c = t0 * M + m8 + rk1;
  float* op = out + (size_t)t0 * M + m8;
  // thr = t/64 exactly: t*2^-6 is exact in f32 for t<=63, and repeated
  // += 2^-6 keeps every partial sum exactly representable.
  float thr = (float)t0 * 0.015625f;

#pragma unroll 1
  for (uint32_t tt = 0; tt < TBATCH; ++tt) {
    const uint32_t b0 = tf2x32_xor(rk0, rk1, ks2, c + 0u);
    const uint32_t b1 = tf2x32_xor(rk0, rk1, ks2, c + 1u);
    const uint32_t b2 = tf2x32_xor(rk0, rk1, ks2, c + 2u);
    const uint32_t b3 = tf2x32_xor(rk0, rk1, ks2, c + 3u);
    const uint32_t b4 = tf2x32_xor(rk0, rk1, ks2, c + 4u);
    const uint32_t b5 = tf2x32_xor(rk0, rk1, ks2, c + 5u);
    const uint32_t b6 = tf2x32_xor(rk0, rk1, ks2, c + 6u);
    const uint32_t b7 = tf2x32_xor(rk0, rk1, ks2, c + 7u);

    float4 oa, ob;
    oa.x = ((xa.x <= thr) && (b0 <= BITS_LE)) ? 1.0f : 0.0f;
    oa.y = ((xa.y <= thr) && (b1 <= BITS_LE)) ? 1.0f : 0.0f;
    oa.z = ((xa.z <= thr) && (b2 <= BITS_LE)) ? 1.0f : 0.0f;
    oa.w = ((xa.w <= thr) && (b3 <= BITS_LE)) ? 1.0f : 0.0f;
    ob.x = ((xb.x <= thr) && (b4 <= BITS_LE)) ? 1.0f : 0.0f;
    ob.y = ((xb.y <= thr) && (b5 <= BITS_LE)) ? 1.0f : 0.0f;
    ob.z = ((xb.z <= thr) && (b6 <= BITS_LE)) ? 1.0f : 0.0f;
    ob.w = ((xb.w <= thr) && (b7 <= BITS_LE)) ? 1.0f : 0.0f;

    float4* o4 = reinterpret_cast<float4*>(op);
    o4[0] = oa;
    o4[1] = ob;

    c += M;
    op += M;
    thr += 0.015625f;
  }
}

// Host-side full threefry2x32 (both words) for the fold_in key derivation.
static inline void tf2x32_host(uint32_t k0, uint32_t k1, uint32_t& x0, uint32_t& x1) {
  const uint32_t ks2 = k0 ^ k1 ^ 0x1BD11BDAu;
  x0 += k0; x1 += k1;
  auto rnd = [&](int r) { x0 += x1; x1 = (x1 << r) | (x1 >> (32 - r)); x1 ^= x0; };
  rnd(13); rnd(15); rnd(26); rnd(6);  x0 += k1;  x1 += ks2 + 1u;
  rnd(17); rnd(29); rnd(16); rnd(24); x0 += ks2; x1 += k0 + 2u;
  rnd(13); rnd(15); rnd(26); rnd(6);  x0 += k0;  x1 += k1 + 3u;
  rnd(17); rnd(29); rnd(16); rnd(24); x0 += k1;  x1 += ks2 + 4u;
  rnd(13); rnd(15); rnd(26); rnd(6);  x0 += ks2; x1 += k0 + 5u;
}

extern "C" void kernel_launch(void* const* d_in, const int* in_sizes, int n_in,
                              void* d_out, int out_size, void* d_ws, size_t ws_size,
                              hipStream_t stream) {
  (void)in_sizes; (void)n_in; (void)out_size; (void)d_ws; (void)ws_size;
  const float* x = (const float*)d_in[0];
  float* out = (float*)d_out;

  // rkey = fold_in(key(0), 1) = threefry2x32(key=(0,0), counts=(0,1))
  uint32_t rk0 = 0u, rk1 = 1u;
  tf2x32_host(0u, 0u, rk0, rk1);

  dim3 grid(M / 8u / 256u, T / TBATCH);  // (1176, 4)
  spike_encode<<<grid, dim3(256), 0, stream>>>(x, out, rk0, rk1);
}

// Round 7
// 747.749 us; speedup vs baseline: 1.1378x; 1.1378x over previous
//
#include <hip/hip_runtime.h>
#include <stdint.h>

// Problem: out[t,b,c,h,w] = (t - 64*x >= 0) * (uniform(fold_in(key(0),1)) <= 0.75)
// out shape (64,16,3,224,224) fp32; N = 154,140,672 < 2^32.
//
// Status: VALU-issue-bound on the irreducible 20-round threefry
// (VALUBusy 92.6% measured R6; absmax=0 across all rounds).
// R5 (unrolled TBATCH=4, alignbit asm): 714.5 us total, spike ~324 us.
// R6 (rolled TBATCH=16): 850.8, spike 404 us @ 92.6% busy -> rolled-loop
// codegen regresses despite identical static op count. R7 removes the
// confound entirely: TBATCH=1, flat ~640-instr body (~5.5 KB I-footprint),
// no loop-carried state, low VGPR -> max occupancy.
static constexpr uint32_t M = 16u * 3u * 224u * 224u;  // 2,408,448 per timestep

// uniform = bitcast((bits>>9)|0x3F800000)-1 <= 0.75  <=>  bits <= 0xC00001FF
static constexpr uint32_t BITS_LE = 0xC00001FFu;

// One threefry round: x0 += x1; x1 = rotl(x1, 32-COMPL); x1 ^= x0.
// COMPL = complement shift, inline constant (free in src2).
#define TF_RND(COMPL)                                                   \
  x0 += x1;                                                             \
  asm("v_alignbit_b32 %0, %1, %1, " #COMPL : "=v"(x1) : "v"(x1));       \
  x1 ^= x0;

// Threefry-2x32, 20 rounds, counts=(0,j). JAX partitionable random_bits
// returns x0^x1. x0 starts at 0 so the key-inject is x0=k0; x1 arrives
// pre-injected (= j + k1). Rotations 13,15,26,6 / 17,29,16,24 ->
// complements 19,17,6,26 / 15,3,16,8. Bit-exact on HW (R0/R3/R4/R5/R6).
__device__ __forceinline__ uint32_t tf2x32_xor(uint32_t k0, uint32_t k1,
                                               uint32_t ks2, uint32_t x1) {
  uint32_t x0 = k0;
  TF_RND(19) TF_RND(17) TF_RND(6)  TF_RND(26)
  x0 += k1;  x1 += ks2 + 1u;
  TF_RND(15) TF_RND(3)  TF_RND(16) TF_RND(8)
  x0 += ks2; x1 += k0 + 2u;
  TF_RND(19) TF_RND(17) TF_RND(6)  TF_RND(26)
  x0 += k0;  x1 += k1 + 3u;
  TF_RND(15) TF_RND(3)  TF_RND(16) TF_RND(8)
  x0 += k1;  x1 += ks2 + 4u;
  TF_RND(19) TF_RND(17) TF_RND(6)  TF_RND(26)
  x0 += ks2; x1 += k0 + 5u;
  return x0 ^ x1;
}

// grid = (M/8/256, 64) = (1176, 64); blockIdx.y = timestep t.
// Each thread: 8 consecutive spatial elements, one timestep. Flat body,
// 8 independent threefry chains for ILP, two float4 loads/stores.
__global__ __launch_bounds__(256) void spike_encode(
    const float* __restrict__ x, float* __restrict__ out,
    uint32_t rk0, uint32_t rk1) {
  const uint32_t m8 = (blockIdx.x * 256u + threadIdx.x) * 8u;
  const uint32_t t  = blockIdx.y;
  // (t - 64x >= 0) <=> (x <= t/64): exact pow2 scalings, fp subtract sign
  // is exact => bit-identical condition. thr is wave-uniform (SGPR).
  const float thr = (float)t * 0.015625f;

  const float4 xa = *reinterpret_cast<const float4*>(x + m8);
  const float4 xb = *reinterpret_cast<const float4*>(x + m8 + 4);

  const uint32_t ks2 = rk0 ^ rk1 ^ 0x1BD11BDAu;
  const uint32_t c   = t * M + m8 + rk1;  // pre-injected count base

  const uint32_t b0 = tf2x32_xor(rk0, rk1, ks2, c + 0u);
  const uint32_t b1 = tf2x32_xor(rk0, rk1, ks2, c + 1u);
  const uint32_t b2 = tf2x32_xor(rk0, rk1, ks2, c + 2u);
  const uint32_t b3 = tf2x32_xor(rk0, rk1, ks2, c + 3u);
  const uint32_t b4 = tf2x32_xor(rk0, rk1, ks2, c + 4u);
  const uint32_t b5 = tf2x32_xor(rk0, rk1, ks2, c + 5u);
  const uint32_t b6 = tf2x32_xor(rk0, rk1, ks2, c + 6u);
  const uint32_t b7 = tf2x32_xor(rk0, rk1, ks2, c + 7u);

  float4 oa, ob;
  oa.x = ((xa.x <= thr) && (b0 <= BITS_LE)) ? 1.0f : 0.0f;
  oa.y = ((xa.y <= thr) && (b1 <= BITS_LE)) ? 1.0f : 0.0f;
  oa.z = ((xa.z <= thr) && (b2 <= BITS_LE)) ? 1.0f : 0.0f;
  oa.w = ((xa.w <= thr) && (b3 <= BITS_LE)) ? 1.0f : 0.0f;
  ob.x = ((xb.x <= thr) && (b4 <= BITS_LE)) ? 1.0f : 0.0f;
  ob.y = ((xb.y <= thr) && (b5 <= BITS_LE)) ? 1.0f : 0.0f;
  ob.z = ((xb.z <= thr) && (b6 <= BITS_LE)) ? 1.0f : 0.0f;
  ob.w = ((xb.w <= thr) && (b7 <= BITS_LE)) ? 1.0f : 0.0f;

  float4* o4 = reinterpret_cast<float4*>(out + (size_t)t * M + m8);
  o4[0] = oa;
  o4[1] = ob;
}

// Host-side full threefry2x32 (both words) for the fold_in key derivation.
static inline void tf2x32_host(uint32_t k0, uint32_t k1, uint32_t& x0, uint32_t& x1) {
  const uint32_t ks2 = k0 ^ k1 ^ 0x1BD11BDAu;
  x0 += k0; x1 += k1;
  auto rnd = [&](int r) { x0 += x1; x1 = (x1 << r) | (x1 >> (32 - r)); x1 ^= x0; };
  rnd(13); rnd(15); rnd(26); rnd(6);  x0 += k1;  x1 += ks2 + 1u;
  rnd(17); rnd(29); rnd(16); rnd(24); x0 += ks2; x1 += k0 + 2u;
  rnd(13); rnd(15); rnd(26); rnd(6);  x0 += k0;  x1 += k1 + 3u;
  rnd(17); rnd(29); rnd(16); rnd(24); x0 += k1;  x1 += ks2 + 4u;
  rnd(13); rnd(15); rnd(26); rnd(6);  x0 += ks2; x1 += k0 + 5u;
}

extern "C" void kernel_launch(void* const* d_in, const int* in_sizes, int n_in,
                              void* d_out, int out_size, void* d_ws, size_t ws_size,
                              hipStream_t stream) {
  (void)in_sizes; (void)n_in; (void)out_size; (void)d_ws; (void)ws_size;
  const float* x = (const float*)d_in[0];
  float* out = (float*)d_out;

  // rkey = fold_in(key(0), 1) = threefry2x32(key=(0,0), counts=(0,1))
  uint32_t rk0 = 0u, rk1 = 1u;
  tf2x32_host(0u, 0u, rk0, rk1);

  dim3 grid(M / 8u / 256u, 64);  // (1176, 64)
  spike_encode<<<grid, dim3(256), 0, stream>>>(x, out, rk0, rk1);
}

// Round 8
// 719.958 us; speedup vs baseline: 1.1817x; 1.0386x over previous
//
#include <hip/hip_runtime.h>
#include <stdint.h>

// Problem: out[t,b,c,h,w] = (t - 64*x >= 0) * (uniform(fold_in(key(0),1)) <= 0.75)
// out shape (64,16,3,224,224) fp32; N = 154,140,672 < 2^32.
//
// Shape ranking (spike portion): TBATCH=4 unrolled 324 us (R5, best) <
// TBATCH=1 flat 357 (R7) < TBATCH=16 rolled 404 (R6, VALUBusy 92.6%).
// R8 = exact R5 shape + ONE change: the rotate asm uses a tied "+v"
// constraint (%0,%0,%0) so the register allocator cannot insert a v_mov
// per rotate (previous "=v"/"v" pair permitted up to 20 movs/chain =
// +26% instruction stream). Bit-exact: alignbit(x,x,32-r) == rotl(x,r).
static constexpr uint32_t T = 64;
static constexpr uint32_t M = 16u * 3u * 224u * 224u;  // 2,408,448 per timestep
static constexpr uint32_t TBATCH = 4;

// uniform = bitcast((bits>>9)|0x3F800000)-1 <= 0.75  <=>  bits <= 0xC00001FF
static constexpr uint32_t BITS_LE = 0xC00001FFu;

// One threefry round: x0 += x1; x1 = rotl(x1, 32-COMPL); x1 ^= x0.
// COMPL = complement shift, inline constant (free in src2). Tied "+v"
// guarantees in-place rotate (no allocator mov).
#define TF_RND(COMPL)                                                   \
  x0 += x1;                                                             \
  asm("v_alignbit_b32 %0, %0, %0, " #COMPL : "+v"(x1));                 \
  x1 ^= x0;

// Threefry-2x32, 20 rounds, counts=(0,j). JAX partitionable random_bits
// returns x0^x1. x0 starts at 0 so the key-inject is x0=k0; x1 arrives
// pre-injected (= j + k1). Rotations 13,15,26,6 / 17,29,16,24 ->
// complements 19,17,6,26 / 15,3,16,8. Bit-exact on HW (R0/R3-R7).
__device__ __forceinline__ uint32_t tf2x32_xor(uint32_t k0, uint32_t k1,
                                               uint32_t ks2, uint32_t x1) {
  uint32_t x0 = k0;
  TF_RND(19) TF_RND(17) TF_RND(6)  TF_RND(26)
  x0 += k1;  x1 += ks2 + 1u;
  TF_RND(15) TF_RND(3)  TF_RND(16) TF_RND(8)
  x0 += ks2; x1 += k0 + 2u;
  TF_RND(19) TF_RND(17) TF_RND(6)  TF_RND(26)
  x0 += k0;  x1 += k1 + 3u;
  TF_RND(15) TF_RND(3)  TF_RND(16) TF_RND(8)
  x0 += k1;  x1 += ks2 + 4u;
  TF_RND(19) TF_RND(17) TF_RND(6)  TF_RND(26)
  x0 += ks2; x1 += k0 + 5u;
  return x0 ^ x1;
}

// grid = (M/8/256, 16) = (1176, 16); blockIdx.y selects 4 consecutive t.
// Each thread: 8 consecutive spatial elements x 4 timesteps, fully
// unrolled (R5's winning shape).
__global__ __launch_bounds__(256) void spike_encode(
    const float* __restrict__ x, float* __restrict__ out,
    uint32_t rk0, uint32_t rk1) {
  const uint32_t m8 = (blockIdx.x * 256u + threadIdx.x) * 8u;
  const uint32_t t0 = blockIdx.y * TBATCH;

  const float4 xa = *reinterpret_cast<const float4*>(x + m8);
  const float4 xb = *reinterpret_cast<const float4*>(x + m8 + 4);

  const uint32_t ks2 = rk0 ^ rk1 ^ 0x1BD11BDAu;
  // Pre-injected count base for (t0, m8); advance by M per timestep.
  uint32_t c = t0 * M + m8 + rk1;

#pragma unroll
  for (uint32_t tt = 0; tt < TBATCH; ++tt) {
    const uint32_t t = t0 + tt;
    // (t - 64x >= 0) <=> (x <= t/64): exact pow2 scalings, fp subtract sign
    // is exact => bit-identical condition.
    const float thr = (float)t * 0.015625f;

    const uint32_t b0 = tf2x32_xor(rk0, rk1, ks2, c + 0u);
    const uint32_t b1 = tf2x32_xor(rk0, rk1, ks2, c + 1u);
    const uint32_t b2 = tf2x32_xor(rk0, rk1, ks2, c + 2u);
    const uint32_t b3 = tf2x32_xor(rk0, rk1, ks2, c + 3u);
    const uint32_t b4 = tf2x32_xor(rk0, rk1, ks2, c + 4u);
    const uint32_t b5 = tf2x32_xor(rk0, rk1, ks2, c + 5u);
    const uint32_t b6 = tf2x32_xor(rk0, rk1, ks2, c + 6u);
    const uint32_t b7 = tf2x32_xor(rk0, rk1, ks2, c + 7u);

    float4 oa, ob;
    oa.x = ((xa.x <= thr) && (b0 <= BITS_LE)) ? 1.0f : 0.0f;
    oa.y = ((xa.y <= thr) && (b1 <= BITS_LE)) ? 1.0f : 0.0f;
    oa.z = ((xa.z <= thr) && (b2 <= BITS_LE)) ? 1.0f : 0.0f;
    oa.w = ((xa.w <= thr) && (b3 <= BITS_LE)) ? 1.0f : 0.0f;
    ob.x = ((xb.x <= thr) && (b4 <= BITS_LE)) ? 1.0f : 0.0f;
    ob.y = ((xb.y <= thr) && (b5 <= BITS_LE)) ? 1.0f : 0.0f;
    ob.z = ((xb.z <= thr) && (b6 <= BITS_LE)) ? 1.0f : 0.0f;
    ob.w = ((xb.w <= thr) && (b7 <= BITS_LE)) ? 1.0f : 0.0f;

    float4* o4 = reinterpret_cast<float4*>(out + (size_t)(t)*M + m8);
    o4[0] = oa;
    o4[1] = ob;

    c += M;
  }
}

// Host-side full threefry2x32 (both words) for the fold_in key derivation.
static inline void tf2x32_host(uint32_t k0, uint32_t k1, uint32_t& x0, uint32_t& x1) {
  const uint32_t ks2 = k0 ^ k1 ^ 0x1BD11BDAu;
  x0 += k0; x1 += k1;
  auto rnd = [&](int r) { x0 += x1; x1 = (x1 << r) | (x1 >> (32 - r)); x1 ^= x0; };
  rnd(13); rnd(15); rnd(26); rnd(6);  x0 += k1;  x1 += ks2 + 1u;
  rnd(17); rnd(29); rnd(16); rnd(24); x0 += ks2; x1 += k0 + 2u;
  rnd(13); rnd(15); rnd(26); rnd(6);  x0 += k0;  x1 += k1 + 3u;
  rnd(17); rnd(29); rnd(16); rnd(24); x0 += k1;  x1 += ks2 + 4u;
  rnd(13); rnd(15); rnd(26); rnd(6);  x0 += ks2; x1 += k0 + 5u;
}

extern "C" void kernel_launch(void* const* d_in, const int* in_sizes, int n_in,
                              void* d_out, int out_size, void* d_ws, size_t ws_size,
                              hipStream_t stream) {
  (void)in_sizes; (void)n_in; (void)out_size; (void)d_ws; (void)ws_size;
  const float* x = (const float*)d_in[0];
  float* out = (float*)d_out;

  // rkey = fold_in(key(0), 1) = threefry2x32(key=(0,0), counts=(0,1))
  uint32_t rk0 = 0u, rk1 = 1u;
  tf2x32_host(0u, 0u, rk0, rk1);

  dim3 grid(M / 8u / 256u, T / TBATCH);  // (1176, 16)
  spike_encode<<<grid, dim3(256), 0, stream>>>(x, out, rk0, rk1);
}